// Round 1
// baseline (2997.893 us; speedup 1.0000x reference)
//
#include <hip/hip_runtime.h>
#include <math.h>

#define HID 64
#define UH_LEN 15
#define N_INC 4

__device__ __forceinline__ float frcp(float x){ return __builtin_amdgcn_rcpf(x); }
__device__ __forceinline__ float sigf(float x){ return frcp(1.0f + __expf(-x)); }
__device__ __forceinline__ float tanhfast(float x){ return 1.0f - 2.0f*frcp(__expf(2.0f*x)+1.0f); }

// param bound tables (order = PARAM_SPECS)
__device__ const float PLO[30] = {0.5f,0.7f,-2.0f,0.5f,0.05f,0.03f,0.0f,0.1f,0.02f,0.05f,0.0f,
                                  10.0f,5.0f,10.0f,10.0f,5.0f,0.1f,0.001f,0.01f,5.0f,1.0f,0.0f,
                                  0.0f,0.0f,0.0f,0.0f,0.0f,0.0f,1.0f,0.5f};
__device__ const float PHI[30] = {2.0f,1.4f,2.0f,2.0f,0.49f,0.19f,1.0f,1.0f,0.3f,0.5f,0.3f,
                                  300.0f,150.0f,500.0f,1000.0f,400.0f,0.75f,0.05f,0.35f,350.0f,5.0f,0.8f,
                                  0.1f,0.4f,0.2f,0.5f,0.4f,1.0f,6.0f,5.0f};
__device__ const float LOGT[15] = {0.0f,0.69314718f,1.09861229f,1.38629436f,1.60943791f,
                                   1.79175947f,1.94591015f,2.07944154f,2.19722458f,2.30258509f,
                                   2.39789527f,2.48490665f,2.56494936f,2.63905733f,2.70805020f};

__global__ void zero_kernel(float* __restrict__ p, int cnt){
    int i = blockIdx.x*256 + threadIdx.x;
    if (i < cnt) p[i] = 0.0f;
}

// ---------------------------------------------------------------------------
// LSTM parameter net. Block = 256 threads = 4 waves; each wave owns 2 units.
// Whh staged in LDS as [j][lane] -> float4 over gates (i,f,g,o).
// ---------------------------------------------------------------------------
__global__ __launch_bounds__(256, 2) void lstm_kernel(
    const float* __restrict__ x_dyn,    // [N][T][8]
    const float* __restrict__ x_static, // [N][16]
    const float* __restrict__ Wih,      // [256][8]
    const float* __restrict__ Whh,      // [256][64]
    const float* __restrict__ b_lstm,   // [256]
    const float* __restrict__ Ws,       // [64][16]
    const float* __restrict__ bs,       // [64]
    const float* __restrict__ Wout,     // [30][128]
    const float* __restrict__ bout,     // [30]
    float* __restrict__ params,         // [30][N]
    int N, int T, int DSTAT)
{
    __shared__ float4 Wh4[64*64];           // 64 KiB: [j*64+lane] -> gates
    __shared__ float4 Wi4[8*64];            // 8 KiB:  [k*64+lane] -> gates
    __shared__ float2 h2[4][64];            // per-wave h for 2 units
    __shared__ float2 x2[4][8];             // per-wave xt for 2 units

    const int tid = threadIdx.x;
    const int wv = tid >> 6;
    const int ln = tid & 63;
    const int u0 = blockIdx.x*8 + wv*2;     // first of this wave's 2 units

    // stage Whh transposed: Wh4[j*64+l].gate_g = Whh[(g*64+l)*64 + j]
    for (int idx = tid; idx < 64*64; idx += 256) {
        int j = idx >> 6, l = idx & 63;
        float4 w;
        w.x = Whh[( 0*64 + l)*64 + j];
        w.y = Whh[( 1*64 + l)*64 + j];
        w.z = Whh[( 2*64 + l)*64 + j];
        w.w = Whh[( 3*64 + l)*64 + j];
        Wh4[idx] = w;
    }
    for (int idx = tid; idx < 8*64; idx += 256) {
        int k = idx >> 6, l = idx & 63;
        float4 w;
        w.x = Wih[( 0*64 + l)*8 + k];
        w.y = Wih[( 1*64 + l)*8 + k];
        w.z = Wih[( 2*64 + l)*8 + k];
        w.w = Wih[( 3*64 + l)*8 + k];
        Wi4[idx] = w;
    }
    const float b0 = b_lstm[      ln];
    const float b1 = b_lstm[ 64 + ln];
    const float b2 = b_lstm[128 + ln];
    const float b3 = b_lstm[192 + ln];
    h2[wv][ln] = make_float2(0.0f, 0.0f);
    float c0 = 0.0f, c1 = 0.0f;
    __syncthreads();

    const int uA = min(u0,     N-1);
    const int uB = min(u0 + 1, N-1);

    for (int t = 0; t < T; ++t) {
        if (ln < 16) {
            int u = ln >> 3, k = ln & 7;
            int uu = u ? uB : uA;
            ((float*)&x2[wv][k])[u] = x_dyn[((size_t)uu*T + t)*8 + k];
        }
        __syncthreads();
        float a00=b0, a01=b1, a02=b2, a03=b3;
        float a10=b0, a11=b1, a12=b2, a13=b3;
        #pragma unroll
        for (int k = 0; k < 8; ++k) {
            float2 xv = x2[wv][k];
            float4 w  = Wi4[(k<<6) | ln];
            a00=fmaf(xv.x,w.x,a00); a01=fmaf(xv.x,w.y,a01); a02=fmaf(xv.x,w.z,a02); a03=fmaf(xv.x,w.w,a03);
            a10=fmaf(xv.y,w.x,a10); a11=fmaf(xv.y,w.y,a11); a12=fmaf(xv.y,w.z,a12); a13=fmaf(xv.y,w.w,a13);
        }
        #pragma unroll 16
        for (int j = 0; j < 64; ++j) {
            float2 hv = h2[wv][j];
            float4 w  = Wh4[(j<<6) | ln];
            a00=fmaf(hv.x,w.x,a00); a01=fmaf(hv.x,w.y,a01); a02=fmaf(hv.x,w.z,a02); a03=fmaf(hv.x,w.w,a03);
            a10=fmaf(hv.y,w.x,a10); a11=fmaf(hv.y,w.y,a11); a12=fmaf(hv.y,w.z,a12); a13=fmaf(hv.y,w.w,a13);
        }
        float ig0=sigf(a00), fg0=sigf(a01), gg0=tanhfast(a02), og0=sigf(a03);
        c0 = fg0*c0 + ig0*gg0;
        float nh0 = og0*tanhfast(c0);
        float ig1=sigf(a10), fg1=sigf(a11), gg1=tanhfast(a12), og1=sigf(a13);
        c1 = fg1*c1 + ig1*gg1;
        float nh1 = og1*tanhfast(c1);
        __syncthreads();
        h2[wv][ln] = make_float2(nh0, nh1);
    }
    __syncthreads();

    // static encoder: s = tanh(x_static @ Ws.T + bs); reuse Wh4 space as scratch
    float* s_sh = (float*)Wh4;   // [4 waves * 2 units][64]
    {
        const float bsl = bs[ln];
        #pragma unroll
        for (int u = 0; u < 2; ++u) {
            int uu = u ? uB : uA;
            float acc = bsl;
            for (int k = 0; k < DSTAT; ++k)
                acc = fmaf(x_static[(size_t)uu*DSTAT + k], Ws[ln*DSTAT + k], acc);
            s_sh[(wv*2 + u)*64 + ln] = tanhfast(acc);
        }
    }
    __syncthreads();

    // output head: raw = [h;s] @ Wout.T + bout, lanes 0..29 = params
    if (ln < 30) {
        #pragma unroll
        for (int u = 0; u < 2; ++u) {
            int unit = u0 + u;
            if (unit < N) {
                float raw = bout[ln];
                #pragma unroll 8
                for (int m = 0; m < 64; ++m) {
                    float hm = ((const float*)&h2[wv][m])[u];
                    float sm = s_sh[(wv*2 + u)*64 + m];
                    raw = fmaf(hm, Wout[ln*128 + m],      raw);
                    raw = fmaf(sm, Wout[ln*128 + 64 + m], raw);
                }
                float g = sigf(raw);
                params[ln*N + unit] = PLO[ln] + g*(PHI[ln] - PLO[ln]);
            }
        }
    }
}

// ---------------------------------------------------------------------------
// Fused physics: PET + Snow17 + SAC-SMA + UH routing + segment-sum atomics.
// One thread per unit (serial over T).
// ---------------------------------------------------------------------------
__global__ __launch_bounds__(64, 1) void physics_kernel(
    const float* __restrict__ prcp, const float* __restrict__ tavg,
    const int*   __restrict__ doy,  const float* __restrict__ elev_m,
    const float* __restrict__ lat_rad, const float* __restrict__ area_w,
    const int*   __restrict__ basin_idx, const float* __restrict__ P,
    float* __restrict__ out, int N, int T, int B)
{
    int n = blockIdx.x*64 + threadIdx.x;
    if (n >= N) return;

    const float HAMON = P[ 0*N+n], SCF   = P[ 1*N+n], PXTEMP= P[ 2*N+n];
    const float MFMAX = P[ 3*N+n], MFMIN = P[ 4*N+n], UADJ  = P[ 5*N+n];
    const float MBASE = P[ 6*N+n], TIPM  = P[ 7*N+n], PLWHC = P[ 8*N+n];
    const float NMF   = P[ 9*N+n], DAYGM = P[10*N+n];
    const float UZTWM = P[11*N+n], UZFWM = P[12*N+n], LZTWM = P[13*N+n];
    const float LZFPM = P[14*N+n], LZFSM = P[15*N+n], UZK   = P[16*N+n];
    const float LZPK  = P[17*N+n], LZSK  = P[18*N+n], ZPERC = P[19*N+n];
    const float REXP  = P[20*N+n], PFREE = P[21*N+n], PCTIM = P[22*N+n];
    const float ADIMP = P[23*N+n], SIDE  = P[25*N+n];
    const float UH_N  = P[28*N+n], UH_TAU= P[29*N+n];

    const float pa_fac = __expf(-elev_m[n] * (1.0f/8434.0f));
    const float tanlat = __tanf(lat_rad[n]);
    const float wA     = area_w[n];
    const int   bi     = basin_idx[n];

    // UH weights
    float uh[UH_LEN]; float uhs = 0.0f;
    const float inv_tau = frcp(UH_TAU);
    #pragma unroll
    for (int l = 0; l < UH_LEN; ++l) {
        float tl = (float)(l+1);
        uh[l] = __expf((UH_N - 1.0f)*LOGT[l] - tl*inv_tau);
        uhs += uh[l];
    }
    float inv_uhs = frcp(uhs);
    #pragma unroll
    for (int l = 0; l < UH_LEN; ++l) uh[l] *= inv_uhs;

    const float dt        = 1.0f / (float)N_INC;
    const float percm     = LZFPM*LZPK + LZFSM*LZSK;
    const float lz_max    = LZTWM + LZFPM + LZFSM;
    const float twm_sum   = UZTWM + LZTWM;
    const float inv_uztwm = frcp(UZTWM);
    const float inv_twm   = frcp(twm_sum);
    const float inv_uzfwm = frcp(UZFWM);
    const float inv_lzmax = frcp(lz_max);
    const float inv_side  = frcp(1.0f + SIDE);
    const float pinc_fac  = (1.0f - PCTIM - ADIMP)*dt;

    // states
    float wi = 0.0f, wq = 0.0f, ati = 0.0f;
    float uztwc = 0.5f*UZTWM, uzfwc = 0.5f*UZFWM, lztwc = 0.5f*LZTWM;
    float lzfpc = 0.5f*LZFPM, lzfsc = 0.5f*LZFSM, adimc = 0.5f*twm_sum;
    float hist[UH_LEN-1];
    #pragma unroll
    for (int l = 0; l < UH_LEN-1; ++l) hist[l] = 0.0f;

    float* q_gauge = out;
    float* q_base  = out + (size_t)B*T;
    float* q_unit  = out + (size_t)2*B*T;

    const float TWO_PI_365 = 2.0f*3.14159265358979f/365.0f;
    const float TWO_PI_366 = 2.0f*3.14159265358979f/366.0f;
    const float H24_PI     = 24.0f/3.14159265358979f;

    for (int t = 0; t < T; ++t) {
        const float pr = prcp[(size_t)n*T + t];
        const float ta = tavg[(size_t)n*T + t];
        const float dy = (float)doy[(size_t)n*T + t];

        // --- Hamon PET ---
        float decl  = 0.4093f*__sinf(TWO_PI_365*dy - 1.405f);
        float cosw  = fminf(fmaxf(-tanlat*__tanf(decl), -0.9999f), 0.9999f);
        float daylen= acosf(cosw)*H24_PI;
        float esat  = 0.6108f*__expf(17.27f*ta*frcp(ta + 237.3f));
        float pet   = fmaxf(HAMON*29.8f*daylen*esat*frcp(ta + 273.2f), 0.0f);

        // --- Snow17 ---
        bool is_snow = (ta <= PXTEMP);
        float ps    = is_snow ? pr*SCF : 0.0f;
        float prain = is_snow ? 0.0f   : pr;
        wi += ps;
        float mf   = 0.5f*(MFMAX + MFMIN) + 0.5f*(MFMAX - MFMIN)*__sinf(TWO_PI_366*dy);
        ati += TIPM*(fminf(ta, 0.0f) - ati);
        float mros = UADJ*pa_fac*fmaxf(ta, 0.0f)*((!is_snow && wi > 0.0f) ? prain : 0.0f)*0.0125f;
        float melt = fminf(fmaxf(mf*fmaxf(ta - MBASE, 0.0f) + mros - NMF*fmaxf(-ati, 0.0f), 0.0f), wi);
        wi -= melt;
        float gm = fminf(DAYGM, wi);
        wi -= gm;
        float rop   = (wi > 0.0f) ? prain : 0.0f;
        float rfree = prain - rop;
        wq += melt + rop;
        float outq = fmaxf(wq - PLWHC*wi, 0.0f);
        wq -= outq;
        float eff = outq + gm + rfree;

        // --- SAC-SMA ---
        float e  = pet;
        float e1 = fminf(e*uztwc*inv_uztwm, uztwc);
        uztwc -= e1;
        float red = e - e1;
        float e2 = fminf(red, uzfwc);
        uzfwc -= e2; red -= e2;
        float e3 = fminf(red*lztwc*inv_twm, lztwc);
        lztwc -= e3;
        float roimp  = eff*PCTIM;
        float padimp = eff*ADIMP;
        adimc += padimp;
        float ratio = fminf(fmaxf(adimc*inv_twm, 0.0f), 1.0f);
        float adsur = padimp*ratio*ratio;
        adimc = fminf(adimc - adsur, twm_sum);
        float surf = roimp + adsur;
        float base = 0.0f;
        float pinc = eff*pinc_fac;
        #pragma unroll
        for (int inc = 0; inc < N_INC; ++inc) {
            float bfp = lzfpc*LZPK*dt;
            float bfs = lzfsc*LZSK*dt;
            lzfpc -= bfp; lzfsc -= bfs;
            base += (bfp + bfs)*inv_side;
            float qif = uzfwc*UZK*dt;
            uzfwc -= qif; surf += qif;
            float lz_def = (LZTWM - lztwc) + (LZFPM - lzfpc) + (LZFSM - lzfsc);
            float defr = fminf(fmaxf(lz_def*inv_lzmax, 1e-6f), 1.0f);
            float perc = percm*(1.0f + ZPERC*__expf(REXP*__logf(defr)))*dt*uzfwc*inv_uzfwm;
            perc = fminf(fminf(perc, uzfwc), fmaxf(lz_def, 0.0f));
            uzfwc -= perc;
            float pfree = perc*PFREE;
            lztwc += perc - pfree;
            float ex = fmaxf(lztwc - LZTWM, 0.0f);
            lztwc -= ex; pfree += ex;
            float dp  = fmaxf(LZFPM - lzfpc, 0.0f);
            float dsx = fmaxf(LZFSM - lzfsc, 0.0f);
            float fr  = dp*frcp(fmaxf(dp + dsx, 1e-6f));
            lzfpc += pfree*fr;
            lzfsc += pfree*(1.0f - fr);
            float exq = fmaxf(lzfpc - LZFPM, 0.0f);
            lzfpc -= exq; lzfsc += exq;
            float exs = fmaxf(lzfsc - LZFSM, 0.0f);
            lzfsc -= exs; surf += exs;
            uztwc += pinc;
            float exu = fmaxf(uztwc - UZTWM, 0.0f);
            uztwc -= exu; uzfwc += exu;
            float exf = fmaxf(uzfwc - UZFWM, 0.0f);
            uzfwc -= exf; surf += exf;
        }

        // --- routing (register ring buffer) ---
        float q = uh[0]*surf;
        #pragma unroll
        for (int l = 1; l < UH_LEN; ++l) q = fmaf(uh[l], hist[l-1], q);
        #pragma unroll
        for (int l = UH_LEN-2; l >= 1; --l) hist[l] = hist[l-1];
        hist[0] = surf;
        q += base;

        q_unit[(size_t)n*T + t] = q;
        atomicAdd(&q_gauge[(size_t)bi*T + t], q*wA);
        atomicAdd(&q_base [(size_t)bi*T + t], base*wA);
    }
}

extern "C" void kernel_launch(void* const* d_in, const int* in_sizes, int n_in,
                              void* d_out, int out_size, void* d_ws, size_t ws_size,
                              hipStream_t stream) {
    const float* x_dyn    = (const float*)d_in[0];
    const float* x_static = (const float*)d_in[1];
    const float* prcp     = (const float*)d_in[2];
    const float* tavg     = (const float*)d_in[3];
    const int*   doy      = (const int*)  d_in[4];
    const float* elev_m   = (const float*)d_in[5];
    const float* lat_rad  = (const float*)d_in[6];
    const float* area_w   = (const float*)d_in[7];
    const int*   basin_ix = (const int*)  d_in[8];
    // d_in[9] = n_basins (device scalar; B derived from out_size instead)
    const float* Wih      = (const float*)d_in[10];
    const float* Whh      = (const float*)d_in[11];
    const float* b_lstm   = (const float*)d_in[12];
    const float* Ws       = (const float*)d_in[13];
    const float* bs       = (const float*)d_in[14];
    const float* Wout     = (const float*)d_in[15];
    const float* bout     = (const float*)d_in[16];

    const int N = in_sizes[7];                 // area_weight: [N]
    const int T = in_sizes[2] / N;             // prcp: [N,T]
    const int DSTAT = in_sizes[1] / N;         // x_static: [N,16]
    const int NT = N * T;
    const int B = (out_size - NT) / (2 * T);

    float* params = (float*)d_ws;              // [30][N]
    float* out    = (float*)d_out;

    const int zc = 2 * B * T;
    zero_kernel<<<(zc + 255)/256, 256, 0, stream>>>(out, zc);

    const int blocks_lstm = (N + 7) / 8;       // 8 units per block (4 waves x 2)
    lstm_kernel<<<blocks_lstm, 256, 0, stream>>>(x_dyn, x_static, Wih, Whh, b_lstm,
                                                 Ws, bs, Wout, bout, params, N, T, DSTAT);

    physics_kernel<<<(N + 63)/64, 64, 0, stream>>>(prcp, tavg, doy, elev_m, lat_rad,
                                                   area_w, basin_ix, params, out, N, T, B);
}